// Round 1
// baseline (1337.991 us; speedup 1.0000x reference)
//
#include <hip/hip_runtime.h>
#include <stdint.h>

#define NE 8
#define NH 128
#define ND 8
#define NCONT 168
#define NHOR 24
#define NB 4096
#define NG 512   // 4*NH
#define BT 64    // batch rows per block

typedef float f32x4 __attribute__((ext_vector_type(4)));
typedef short bf16x8 __attribute__((ext_vector_type(8)));

__device__ __forceinline__ unsigned short f2bf(float f){
  union { float f; unsigned u; } v; v.f = f;
  unsigned r = (v.u + 0x7FFFu + ((v.u >> 16) & 1u)) >> 16;
  return (unsigned short)r;
}
__device__ __forceinline__ float bf2f(unsigned short s){
  union { unsigned u; float f; } v; v.u = ((unsigned)s) << 16; return v.f;
}
__device__ __forceinline__ float sigm(float x){
  return __builtin_amdgcn_rcpf(1.0f + __builtin_amdgcn_exp2f(-1.44269504f * x));
}
__device__ __forceinline__ float tanh_fast(float x){
  return 1.0f - 2.0f * __builtin_amdgcn_rcpf(1.0f + __builtin_amdgcn_exp2f(2.88539008f * x));
}

// fxW_enc[e][t][j] = enc_b[e][j] + sum_i feats[t][i] * enc_W[e][1+i][j]
__global__ void prep_fxw_enc(const float* __restrict__ feats, const float* __restrict__ W,
                             const float* __restrict__ bias, float* __restrict__ out){
  int idx = blockIdx.x * blockDim.x + threadIdx.x;
  if (idx >= NE * NCONT * NG) return;
  int j = idx & (NG - 1);
  int t = (idx >> 9) % NCONT;
  int e = idx / (NCONT * NG);
  float s = bias[e * NG + j];
  #pragma unroll
  for (int i = 0; i < ND; ++i)
    s += feats[t * ND + i] * W[(e * 9 + 1 + i) * NG + j];
  out[idx] = s;
}

// fxW_dec[e][t][j] = dec_b[e][j] + sum_i feats[CONT+t][i] * dec_W[e][i][j]
__global__ void prep_fxw_dec(const float* __restrict__ feats, const float* __restrict__ W,
                             const float* __restrict__ bias, float* __restrict__ out){
  int idx = blockIdx.x * blockDim.x + threadIdx.x;
  if (idx >= NE * NHOR * NG) return;
  int j = idx & (NG - 1);
  int t = (idx >> 9) % NHOR;
  int e = idx / (NHOR * NG);
  float s = bias[e * NG + j];
  #pragma unroll
  for (int i = 0; i < ND; ++i)
    s += feats[(NCONT + t) * ND + i] * W[(e * ND + i) * NG + j];
  out[idx] = s;
}

__global__ void prep_node(const int* __restrict__ nid, const float* __restrict__ emb,
                          float* __restrict__ node_w){
  int b = blockIdx.x * blockDim.x + threadIdx.x;
  if (b >= NB) return;
  int n = nid[b];
  float a[NE]; float s = 0.f;
  #pragma unroll
  for (int e = 0; e < NE; ++e){ a[e] = fabsf(emb[n * NE + e]); s += a[e]; }
  float inv = 1.0f / s;
  #pragma unroll
  for (int e = 0; e < NE; ++e) node_w[b * NE + e] = a[e] * inv;
}

// Main kernel: one block = (expert e, 64 batch rows). 512 threads = 8 waves.
// Wave w owns hidden cols [w*16, w*16+16) across all 4 gates, all 64 rows.
// h lives in LDS (bf16, XOR-swizzled, double-buffered); U lives in registers.
__global__ __launch_bounds__(512, 2) void lstm_main(
    const float* __restrict__ y_prev,
    const float* __restrict__ enc_W,
    const float* __restrict__ enc_U,
    const float* __restrict__ dec_U,
    const float* __restrict__ out_w,
    const float* __restrict__ fxw_enc,
    const float* __restrict__ fxw_dec,
    float* __restrict__ ws_out)
{
  __shared__ unsigned short hl[2][BT * NH];  // 2 x 16KB
  __shared__ float ow_lds[NH];

  const int tid  = threadIdx.x;
  const int lane = tid & 63;
  const int w    = tid >> 6;            // wave id 0..7
  const int e    = blockIdx.x & 7;      // expert -> XCD affinity
  const int b0   = (blockIdx.x >> 3) * BT;
  const int l15  = lane & 15;
  const int l4   = lane >> 4;
  const int kcol = w * 16 + l15;        // hidden col this lane owns in gate phase

  // init h[0] = 0, stage out_w
  {
    f32x4 z4 = {0.f, 0.f, 0.f, 0.f};
    ((f32x4*)&hl[0][0])[tid]       = z4;
    ((f32x4*)&hl[0][0])[tid + 512] = z4;
    if (tid < NH) ow_lds[tid] = out_w[e * NH + tid];
  }

  // Load encoder U fragments into registers (bf16).
  // B-frag layout for mfma_f32_16x16x32_bf16: lane holds B[k = 8*(l>>4)+j][col = l&15].
  bf16x8 uf[4][4];  // [gate][kchunk]
  {
    const float* Ug = enc_U + e * NH * NG;
    #pragma unroll
    for (int g = 0; g < 4; ++g)
      #pragma unroll
      for (int kc = 0; kc < 4; ++kc){
        const float* p = Ug + (kc * 32 + l4 * 8) * NG + g * NH + kcol;
        bf16x8 v;
        #pragma unroll
        for (int j = 0; j < 8; ++j) v[j] = (short)f2bf(p[j * NG]);
        uf[g][kc] = v;
      }
  }

  float w0[4];
  #pragma unroll
  for (int g = 0; g < 4; ++g) w0[g] = enc_W[e * 9 * NG + g * NH + kcol];

  float c_s[4][4];  // cell state: [mfrag][reg], hidden col = kcol
  #pragma unroll
  for (int mf = 0; mf < 4; ++mf)
    #pragma unroll
    for (int rg = 0; rg < 4; ++rg) c_s[mf][rg] = 0.f;

  __syncthreads();

  int cur = 0;

  // ---------------- encoder: 168 steps ----------------
  for (int t = 0; t < NCONT; ++t){
    f32x4 acc[4][4];  // z acc: [mfrag][gate]
    #pragma unroll
    for (int mf = 0; mf < 4; ++mf)
      #pragma unroll
      for (int g = 0; g < 4; ++g) acc[mf][g] = (f32x4){0.f,0.f,0.f,0.f};

    #pragma unroll
    for (int kc = 0; kc < 4; ++kc){
      bf16x8 af[4];
      #pragma unroll
      for (int mf = 0; mf < 4; ++mf){
        int row = mf * 16 + l15;
        int eo  = (row * NH + kc * 32 + l4 * 8) ^ ((row & 7) << 3);
        af[mf] = *(const bf16x8*)&hl[cur][eo];
      }
      #pragma unroll
      for (int mf = 0; mf < 4; ++mf)
        #pragma unroll
        for (int g = 0; g < 4; ++g)
          acc[mf][g] = __builtin_amdgcn_mfma_f32_16x16x32_bf16(af[mf], uf[g][kc], acc[mf][g], 0, 0, 0);
    }

    const float* fx = fxw_enc + (e * NCONT + t) * NG;
    float fxv[4];
    #pragma unroll
    for (int g = 0; g < 4; ++g) fxv[g] = fx[g * NH + kcol];

    int nxt = cur ^ 1;
    #pragma unroll
    for (int mf = 0; mf < 4; ++mf){
      f32x4 yv = *(const f32x4*)&y_prev[t * NB + b0 + mf * 16 + l4 * 4];
      #pragma unroll
      for (int rg = 0; rg < 4; ++rg){
        float y  = yv[rg];
        float zi = acc[mf][0][rg] + fxv[0] + y * w0[0];
        float zf = acc[mf][1][rg] + fxv[1] + y * w0[1];
        float zg = acc[mf][2][rg] + fxv[2] + y * w0[2];
        float zo = acc[mf][3][rg] + fxv[3] + y * w0[3];
        float gi = sigm(zi), gf = sigm(zf);
        float gg = tanh_fast(zg), go = sigm(zo);
        float c  = gf * c_s[mf][rg] + gi * gg;
        c_s[mf][rg] = c;
        float h  = go * tanh_fast(c);
        int r = mf * 16 + l4 * 4 + rg;
        hl[nxt][(r * NH + kcol) ^ ((r & 7) << 3)] = f2bf(h);
      }
    }
    cur = nxt;
    __syncthreads();
  }

  // Load decoder U fragments (overwrite regs)
  {
    const float* Ug = dec_U + e * NH * NG;
    #pragma unroll
    for (int g = 0; g < 4; ++g)
      #pragma unroll
      for (int kc = 0; kc < 4; ++kc){
        const float* p = Ug + (kc * 32 + l4 * 8) * NG + g * NH + kcol;
        bf16x8 v;
        #pragma unroll
        for (int j = 0; j < 8; ++j) v[j] = (short)f2bf(p[j * NG]);
        uf[g][kc] = v;
      }
  }

  // ---------------- decoder: 24 steps ----------------
  for (int t = 0; t < NHOR; ++t){
    f32x4 acc[4][4];
    #pragma unroll
    for (int mf = 0; mf < 4; ++mf)
      #pragma unroll
      for (int g = 0; g < 4; ++g) acc[mf][g] = (f32x4){0.f,0.f,0.f,0.f};

    #pragma unroll
    for (int kc = 0; kc < 4; ++kc){
      bf16x8 af[4];
      #pragma unroll
      for (int mf = 0; mf < 4; ++mf){
        int row = mf * 16 + l15;
        int eo  = (row * NH + kc * 32 + l4 * 8) ^ ((row & 7) << 3);
        af[mf] = *(const bf16x8*)&hl[cur][eo];
      }
      #pragma unroll
      for (int mf = 0; mf < 4; ++mf)
        #pragma unroll
        for (int g = 0; g < 4; ++g)
          acc[mf][g] = __builtin_amdgcn_mfma_f32_16x16x32_bf16(af[mf], uf[g][kc], acc[mf][g], 0, 0, 0);
    }

    const float* fx = fxw_dec + (e * NHOR + t) * NG;
    float fxv[4];
    #pragma unroll
    for (int g = 0; g < 4; ++g) fxv[g] = fx[g * NH + kcol];

    int nxt = cur ^ 1;
    #pragma unroll
    for (int mf = 0; mf < 4; ++mf){
      #pragma unroll
      for (int rg = 0; rg < 4; ++rg){
        float zi = acc[mf][0][rg] + fxv[0];
        float zf = acc[mf][1][rg] + fxv[1];
        float zg = acc[mf][2][rg] + fxv[2];
        float zo = acc[mf][3][rg] + fxv[3];
        float gi = sigm(zi), gf = sigm(zf);
        float gg = tanh_fast(zg), go = sigm(zo);
        float c  = gf * c_s[mf][rg] + gi * gg;
        c_s[mf][rg] = c;
        float h  = go * tanh_fast(c);
        int r = mf * 16 + l4 * 4 + rg;
        hl[nxt][(r * NH + kcol) ^ ((r & 7) << 3)] = f2bf(h);
      }
    }
    cur = nxt;
    __syncthreads();

    // out[e][t][r] = sum_k h[r][k] * ow[k]; 8 rows per wave, 8 k-groups per row
    int r  = w * 8 + (lane >> 3);
    int kg = (lane & 7) * 16;
    int e0 = (r * NH + kg)     ^ ((r & 7) << 3);
    int e1 = (r * NH + kg + 8) ^ ((r & 7) << 3);
    bf16x8 ha = *(const bf16x8*)&hl[cur][e0];
    bf16x8 hb = *(const bf16x8*)&hl[cur][e1];
    float s = 0.f;
    #pragma unroll
    for (int j = 0; j < 8; ++j){
      s += bf2f((unsigned short)ha[j]) * ow_lds[kg + j];
      s += bf2f((unsigned short)hb[j]) * ow_lds[kg + 8 + j];
    }
    s += __shfl_xor(s, 1);
    s += __shfl_xor(s, 2);
    s += __shfl_xor(s, 4);
    if ((lane & 7) == 0) ws_out[(e * NHOR + t) * NB + b0 + r] = s;
  }
}

__global__ void finalize(const float* __restrict__ ws_out, const float* __restrict__ node_w,
                         float* __restrict__ out){
  int idx = blockIdx.x * blockDim.x + threadIdx.x;
  if (idx >= NHOR * NB) return;
  int b = idx & (NB - 1);
  float s = 0.f;
  #pragma unroll
  for (int e = 0; e < NE; ++e)
    s += ws_out[e * NHOR * NB + idx] * node_w[b * NE + e];
  out[idx] = s;
}

extern "C" void kernel_launch(void* const* d_in, const int* in_sizes, int n_in,
                              void* d_out, int out_size, void* d_ws, size_t ws_size,
                              hipStream_t stream) {
  const float* feats  = (const float*)d_in[0];
  const float* y_prev = (const float*)d_in[1];
  const int*   nid    = (const int*)  d_in[2];
  const float* emb    = (const float*)d_in[3];
  const float* enc_W  = (const float*)d_in[4];
  const float* enc_U  = (const float*)d_in[5];
  const float* enc_b  = (const float*)d_in[6];
  const float* dec_W  = (const float*)d_in[7];
  const float* dec_U  = (const float*)d_in[8];
  const float* dec_b  = (const float*)d_in[9];
  const float* out_w  = (const float*)d_in[10];
  float* out = (float*)d_out;

  float* ws      = (float*)d_ws;
  float* fxw_enc = ws;                              // 8*168*512 = 688128
  float* fxw_dec = fxw_enc + NE * NCONT * NG;       // 8*24*512  =  98304
  float* node_w  = fxw_dec + NE * NHOR * NG;        // 4096*8    =  32768
  float* ws_out  = node_w + NB * NE;                // 8*24*4096 = 786432

  prep_fxw_enc<<<(NE * NCONT * NG + 255) / 256, 256, 0, stream>>>(feats, enc_W, enc_b, fxw_enc);
  prep_fxw_dec<<<(NE * NHOR * NG + 255) / 256, 256, 0, stream>>>(feats, dec_W, dec_b, fxw_dec);
  prep_node<<<(NB + 255) / 256, 256, 0, stream>>>(nid, emb, node_w);
  lstm_main<<<NE * (NB / BT), 512, 0, stream>>>(y_prev, enc_W, enc_U, dec_U, out_w,
                                                fxw_enc, fxw_dec, ws_out);
  finalize<<<(NHOR * NB + 255) / 256, 256, 0, stream>>>(ws_out, node_w, out);
}

// Round 2
// 1290.278 us; speedup vs baseline: 1.0370x; 1.0370x over previous
//
#include <hip/hip_runtime.h>
#include <stdint.h>
#include <type_traits>

#define NE 8
#define NH 128
#define ND 8
#define NCONT 168
#define NHOR 24
#define NB 4096
#define NG 512   // 4*NH
#define BT 64    // batch rows per block

typedef float f32x4 __attribute__((ext_vector_type(4)));
typedef short bf16x8 __attribute__((ext_vector_type(8)));
typedef unsigned int u32x2 __attribute__((ext_vector_type(2)));

__device__ __forceinline__ unsigned short f2bf(float f){
  union { float f; unsigned u; } v; v.f = f;
  unsigned r = (v.u + 0x7FFFu + ((v.u >> 16) & 1u)) >> 16;
  return (unsigned short)r;
}
__device__ __forceinline__ unsigned cvt_pk_bf16(float lo, float hi){
  unsigned r;
  asm("v_cvt_pk_bf16_f32 %0, %1, %2" : "=v"(r) : "v"(lo), "v"(hi));
  return r;
}
__device__ __forceinline__ float sigm(float x){
  return __builtin_amdgcn_rcpf(1.0f + __builtin_amdgcn_exp2f(-1.44269504f * x));
}
__device__ __forceinline__ float tanh_fast(float x){
  return 1.0f - 2.0f * __builtin_amdgcn_rcpf(1.0f + __builtin_amdgcn_exp2f(2.88539008f * x));
}

__global__ void prep_fxw_enc(const float* __restrict__ feats, const float* __restrict__ W,
                             const float* __restrict__ bias, float* __restrict__ out){
  int idx = blockIdx.x * blockDim.x + threadIdx.x;
  if (idx >= NE * NCONT * NG) return;
  int j = idx & (NG - 1);
  int t = (idx >> 9) % NCONT;
  int e = idx / (NCONT * NG);
  float s = bias[e * NG + j];
  #pragma unroll
  for (int i = 0; i < ND; ++i)
    s += feats[t * ND + i] * W[(e * 9 + 1 + i) * NG + j];
  out[idx] = s;
}

__global__ void prep_fxw_dec(const float* __restrict__ feats, const float* __restrict__ W,
                             const float* __restrict__ bias, float* __restrict__ out){
  int idx = blockIdx.x * blockDim.x + threadIdx.x;
  if (idx >= NE * NHOR * NG) return;
  int j = idx & (NG - 1);
  int t = (idx >> 9) % NHOR;
  int e = idx / (NHOR * NG);
  float s = bias[e * NG + j];
  #pragma unroll
  for (int i = 0; i < ND; ++i)
    s += feats[(NCONT + t) * ND + i] * W[(e * ND + i) * NG + j];
  out[idx] = s;
}

__global__ void prep_node(const int* __restrict__ nid, const float* __restrict__ emb,
                          float* __restrict__ node_w){
  int b = blockIdx.x * blockDim.x + threadIdx.x;
  if (b >= NB) return;
  int n = nid[b];
  float a[NE]; float s = 0.f;
  #pragma unroll
  for (int e = 0; e < NE; ++e){ a[e] = fabsf(emb[n * NE + e]); s += a[e]; }
  float inv = 1.0f / s;
  #pragma unroll
  for (int e = 0; e < NE; ++e) node_w[b * NE + e] = a[e] * inv;
}

// One block = (expert e, 64 batch rows). 512 threads = 8 waves.
// MFMA roles: A = U^T fragments (registers), B = h fragments (LDS), C = z^T.
// C layout: col(l&15) = batch-in-frag, row(l4*4+rg) = hidden col offset -> each
// thread owns 4 CONSECUTIVE hidden cols per batch row => packed b64 h-writes.
__global__ __launch_bounds__(512, 2) void lstm_main(
    const float* __restrict__ y_prev,
    const float* __restrict__ enc_W,
    const float* __restrict__ enc_U,
    const float* __restrict__ dec_U,
    const float* __restrict__ out_w,
    const float* __restrict__ fxw_enc,
    const float* __restrict__ fxw_dec,
    float* __restrict__ ws_out)
{
  __shared__ unsigned short hl[2][BT * NH];  // 2 x 16 KB, XOR-swizzled rows
  __shared__ float part[2][BT][9];           // decoder partials (+1 pad col)

  const int tid  = threadIdx.x;
  const int lane = tid & 63;
  const int w    = tid >> 6;
  const int e    = blockIdx.x & 7;
  const int b0   = (blockIdx.x >> 3) * BT;
  const int l15  = lane & 15;
  const int l4   = lane >> 4;              // 0..3
  const int hc0  = w * 16 + l4 * 4;        // thread's hidden-col base (rg adds 0..3)

  // --- precomputed swizzled LDS byte addresses (invariant across steps) ---
  // read row = nf*16 + l15, elems [kc*32 + 8*l4 .. +7], swizzle ^((row&7)<<3)
  const int q   = (l15 >> 2) & 1;
  const int Ae  = l15 * 128 + ((l4 ^ (l15 & 3)) << 3);
  const int rb0 = 2 * (Ae + q * 32);        // kc even base
  const int rb1 = 2 * (Ae + (1 - q) * 32);  // kc odd base
  // write row = nf*16 + l15, cols [hc0 .. hc0+3]
  const int wb  = 2 * ((l15 * 128 + hc0) ^ ((l15 & 7) << 3));

  // init h buffer 0 = 0
  {
    f32x4 z4 = {0.f, 0.f, 0.f, 0.f};
    ((f32x4*)&hl[0][0])[tid]       = z4;
    ((f32x4*)&hl[0][0])[tid + 512] = z4;
  }

  // A-frags: ut[g][kc], lane holds U[k = 32kc+8*l4+j][128g + w*16 + l15]
  bf16x8 ut[4][4];
  {
    const float* Ub = enc_U + e * NH * NG + w * 16 + l15;
    #pragma unroll
    for (int g = 0; g < 4; ++g)
      #pragma unroll
      for (int kc = 0; kc < 4; ++kc){
        const float* p = Ub + (kc * 32 + l4 * 8) * NG + g * NH;
        bf16x8 v;
        #pragma unroll
        for (int j = 0; j < 8; ++j) v[j] = (short)f2bf(p[j * NG]);
        ut[g][kc] = v;
      }
  }

  // encoder y-weight row (input channel 0): per-thread 4 hidden cols per gate
  f32x4 w04[4];
  #pragma unroll
  for (int g = 0; g < 4; ++g)
    w04[g] = *(const f32x4*)&enc_W[(e * 9) * NG + g * NH + hc0];

  float cs[4][4];   // cell state [nf][rg]
  #pragma unroll
  for (int nf = 0; nf < 4; ++nf)
    #pragma unroll
    for (int rg = 0; rg < 4; ++rg) cs[nf][rg] = 0.f;

  const float* fxe = fxw_enc + e * NCONT * NG;
  const float* yp  = y_prev + b0;

  __syncthreads();

  // ---- one LSTM step; B = source buffer parity (compile-time) ----
  auto step = [&](auto Bc, auto ENCc, const float* fxptr, float* pout){
    constexpr int  B   = decltype(Bc)::value;
    constexpr bool ENC = decltype(ENCc)::value;

    f32x4 fxv[4];
    #pragma unroll
    for (int g = 0; g < 4; ++g) fxv[g] = *(const f32x4*)&fxptr[g * NH + hc0];
    float yv[4];
    if (ENC){
      #pragma unroll
      for (int nf = 0; nf < 4; ++nf) yv[nf] = yp[nf * 16 + l15];
    }

    f32x4 acc[4][4];  // [nf][gate]
    #pragma unroll
    for (int kc = 0; kc < 4; ++kc){
      bf16x8 hb[4];
      #pragma unroll
      for (int nf = 0; nf < 4; ++nf)
        hb[nf] = *(const bf16x8*)((const char*)hl +
                   (B * 16384 + nf * 4096 + (kc >> 1) * 128) + ((kc & 1) ? rb1 : rb0));
      #pragma unroll
      for (int nf = 0; nf < 4; ++nf)
        #pragma unroll
        for (int g = 0; g < 4; ++g){
          if (kc == 0)
            acc[nf][g] = __builtin_amdgcn_mfma_f32_16x16x32_bf16(ut[g][0], hb[nf], fxv[g], 0, 0, 0);
          else
            acc[nf][g] = __builtin_amdgcn_mfma_f32_16x16x32_bf16(ut[g][kc], hb[nf], acc[nf][g], 0, 0, 0);
        }
    }

    #pragma unroll
    for (int nf = 0; nf < 4; ++nf){
      float hh[4];
      #pragma unroll
      for (int rg = 0; rg < 4; ++rg){
        float zi = acc[nf][0][rg];
        float zf = acc[nf][1][rg];
        float zg = acc[nf][2][rg];
        float zo = acc[nf][3][rg];
        if (ENC){
          float y = yv[nf];
          zi += y * w04[0][rg]; zf += y * w04[1][rg];
          zg += y * w04[2][rg]; zo += y * w04[3][rg];
        }
        float gi = sigm(zi), gf = sigm(zf);
        float gg = tanh_fast(zg), go = sigm(zo);
        float c  = gf * cs[nf][rg] + gi * gg;
        cs[nf][rg] = c;
        hh[rg] = go * tanh_fast(c);
      }
      u32x2 pk;
      pk.x = cvt_pk_bf16(hh[0], hh[1]);
      pk.y = cvt_pk_bf16(hh[2], hh[3]);
      *(u32x2*)((char*)hl + ((B ^ 1) * 16384 + nf * 4096) + wb) = pk;
      if (!ENC) pout[nf] = hh[0]*pout[4] + hh[1]*pout[5] + hh[2]*pout[6] + hh[3]*pout[7];
    }
    __syncthreads();
  };

  // ---------------- encoder: 168 steps ----------------
  for (int t = 0; t < NCONT; t += 2){
    step(std::integral_constant<int,0>{}, std::true_type{}, fxe, nullptr);
    fxe += NG; yp += NB;
    step(std::integral_constant<int,1>{}, std::true_type{}, fxe, nullptr);
    fxe += NG; yp += NB;
  }

  // decoder A-frags
  {
    const float* Ub = dec_U + e * NH * NG + w * 16 + l15;
    #pragma unroll
    for (int g = 0; g < 4; ++g)
      #pragma unroll
      for (int kc = 0; kc < 4; ++kc){
        const float* p = Ub + (kc * 32 + l4 * 8) * NG + g * NH;
        bf16x8 v;
        #pragma unroll
        for (int j = 0; j < 8; ++j) v[j] = (short)f2bf(p[j * NG]);
        ut[g][kc] = v;
      }
  }
  f32x4 ow4 = *(const f32x4*)&out_w[e * NH + hc0];

  const float* fxd = fxw_dec + e * NHOR * NG;

  // ---------------- decoder: 24 steps ----------------
  #pragma unroll 1
  for (int td = 0; td < NHOR; td += 2){
    #pragma unroll
    for (int sub = 0; sub < 2; ++sub){
      // pbuf[0..3] = partial out; pbuf[4..7] = ow weights (input)
      float pbuf[8];
      pbuf[4] = ow4[0]; pbuf[5] = ow4[1]; pbuf[6] = ow4[2]; pbuf[7] = ow4[3];
      if (sub == 0)
        step(std::integral_constant<int,0>{}, std::false_type{}, fxd, pbuf);
      else
        step(std::integral_constant<int,1>{}, std::false_type{}, fxd, pbuf);
      fxd += NG;
      int t = td + sub;
      int pb = t & 1;
      // NOTE: part[] writes happened AFTER step's barrier would be wrong; they
      // must be before it. step() ends with __syncthreads, so do reduction on
      // pbuf here (register-only), write part, then one barrier, then store.
      #pragma unroll
      for (int nf = 0; nf < 4; ++nf){
        pbuf[nf] += __shfl_xor(pbuf[nf], 16);
        pbuf[nf] += __shfl_xor(pbuf[nf], 32);
      }
      if (lane < 16){
        #pragma unroll
        for (int nf = 0; nf < 4; ++nf) part[pb][nf * 16 + l15][w] = pbuf[nf];
      }
      __syncthreads();
      if (w == 0){
        float s = 0.f;
        #pragma unroll
        for (int ww = 0; ww < 8; ++ww) s += part[pb][lane][ww];
        ws_out[(e * NHOR + t) * NB + b0 + lane] = s;
      }
    }
  }
}

__global__ void finalize(const float* __restrict__ ws_out, const float* __restrict__ node_w,
                         float* __restrict__ out){
  int idx = blockIdx.x * blockDim.x + threadIdx.x;
  if (idx >= NHOR * NB) return;
  int b = idx & (NB - 1);
  float s = 0.f;
  #pragma unroll
  for (int e = 0; e < NE; ++e)
    s += ws_out[e * NHOR * NB + idx] * node_w[b * NE + e];
  out[idx] = s;
}

extern "C" void kernel_launch(void* const* d_in, const int* in_sizes, int n_in,
                              void* d_out, int out_size, void* d_ws, size_t ws_size,
                              hipStream_t stream) {
  const float* feats  = (const float*)d_in[0];
  const float* y_prev = (const float*)d_in[1];
  const int*   nid    = (const int*)  d_in[2];
  const float* emb    = (const float*)d_in[3];
  const float* enc_W  = (const float*)d_in[4];
  const float* enc_U  = (const float*)d_in[5];
  const float* enc_b  = (const float*)d_in[6];
  const float* dec_W  = (const float*)d_in[7];
  const float* dec_U  = (const float*)d_in[8];
  const float* dec_b  = (const float*)d_in[9];
  const float* out_w  = (const float*)d_in[10];
  float* out = (float*)d_out;

  float* ws      = (float*)d_ws;
  float* fxw_enc = ws;
  float* fxw_dec = fxw_enc + NE * NCONT * NG;
  float* node_w  = fxw_dec + NE * NHOR * NG;
  float* ws_out  = node_w + NB * NE;

  prep_fxw_enc<<<(NE * NCONT * NG + 255) / 256, 256, 0, stream>>>(feats, enc_W, enc_b, fxw_enc);
  prep_fxw_dec<<<(NE * NHOR * NG + 255) / 256, 256, 0, stream>>>(feats, dec_W, dec_b, fxw_dec);
  prep_node<<<(NB + 255) / 256, 256, 0, stream>>>(nid, emb, node_w);
  lstm_main<<<NE * (NB / BT), 512, 0, stream>>>(y_prev, enc_W, enc_U, dec_U, out_w,
                                                fxw_enc, fxw_dec, ws_out);
  finalize<<<(NHOR * NB + 255) / 256, 256, 0, stream>>>(ws_out, node_w, out);
}